// Round 1
// baseline (175.470 us; speedup 1.0000x reference)
//
#include <hip/hip_runtime.h>

// 2-level 2D Haar DWT, fused. x: (96, 512, 512) fp32 (B*C=96 images).
// Each thread: one 4x4 input tile -> 2x2 of h1/v1/d1 + 1 px of a2/h2/v2/d2.
// Out layout (flat, reference return order): a2,h2,v2,d2 (each 96*128*128),
// then h1,v1,d1 (each 96*256*256).

#define KINV 0.7071067811865476f

__global__ __launch_bounds__(256) void haar2_fused_kernel(
    const float* __restrict__ x, float* __restrict__ out, int nimg)
{
    const int tid = blockIdx.x * blockDim.x + threadIdx.x;
    const int total = nimg * 128 * 128;
    if (tid >= total) return;

    const int c2  = tid & 127;          // level-2 col
    const int r2  = (tid >> 7) & 127;   // level-2 row
    const int img = tid >> 14;

    const float* xin = x + (size_t)img * (512 * 512);
    const int row0 = r2 * 4;
    const int col0 = c2 * 4;

    // Load 4x4 tile as four float4 rows (16B/lane, coalesced across c2).
    float p[4][4];
    #pragma unroll
    for (int k = 0; k < 4; ++k) {
        float4 v = *reinterpret_cast<const float4*>(xin + (size_t)(row0 + k) * 512 + col0);
        p[k][0] = v.x; p[k][1] = v.y; p[k][2] = v.z; p[k][3] = v.w;
    }

    // Level 1: four 2x2 quads.
    float aa[2][2], da[2][2], ad[2][2], dd[2][2];
    #pragma unroll
    for (int i = 0; i < 2; ++i) {
        #pragma unroll
        for (int j = 0; j < 2; ++j) {
            const float p00 = p[2*i    ][2*j], p01 = p[2*i    ][2*j+1];
            const float p10 = p[2*i + 1][2*j], p11 = p[2*i + 1][2*j+1];
            // along W (last axis) first, then along H — exactly as reference
            const float sA = (p00 + p01) * KINV;
            const float sB = (p10 + p11) * KINV;
            const float dA = (p00 - p01) * KINV;
            const float dB = (p10 - p11) * KINV;
            aa[i][j] = (sA + sB) * KINV;   // cA1
            da[i][j] = (sA - sB) * KINV;   // cH1 (diff along H)
            ad[i][j] = (dA + dB) * KINV;   // cV1 (diff along W)
            dd[i][j] = (dA - dB) * KINV;   // cD1
        }
    }

    // Output section pointers.
    const size_t n2 = (size_t)nimg * 128 * 128;
    const size_t n1 = (size_t)nimg * 256 * 256;
    float* a2o = out;
    float* h2o = out + n2;
    float* v2o = out + 2 * n2;
    float* d2o = out + 3 * n2;
    float* h1o = out + 4 * n2;
    float* v1o = h1o + n1;
    float* d1o = h1o + 2 * n1;

    // Level-1 detail stores: float2 per row (8B/lane, coalesced across c2).
    const size_t img1 = (size_t)img * 256 * 256;
    #pragma unroll
    for (int i = 0; i < 2; ++i) {
        const size_t off = img1 + (size_t)(2 * r2 + i) * 256 + 2 * c2;
        *reinterpret_cast<float2*>(h1o + off) = make_float2(da[i][0], da[i][1]);
        *reinterpret_cast<float2*>(v1o + off) = make_float2(ad[i][0], ad[i][1]);
        *reinterpret_cast<float2*>(d1o + off) = make_float2(dd[i][0], dd[i][1]);
    }

    // Level 2 from the aa quad (same op order: W first, then H).
    const float s0 = (aa[0][0] + aa[0][1]) * KINV;
    const float d0 = (aa[0][0] - aa[0][1]) * KINV;
    const float s1 = (aa[1][0] + aa[1][1]) * KINV;
    const float d1 = (aa[1][0] - aa[1][1]) * KINV;
    const size_t off2 = (size_t)img * 128 * 128 + (size_t)r2 * 128 + c2;
    a2o[off2] = (s0 + s1) * KINV;
    h2o[off2] = (s0 - s1) * KINV;
    v2o[off2] = (d0 + d1) * KINV;
    d2o[off2] = (d0 - d1) * KINV;
}

extern "C" void kernel_launch(void* const* d_in, const int* in_sizes, int n_in,
                              void* d_out, int out_size, void* d_ws, size_t ws_size,
                              hipStream_t stream) {
    const float* x = (const float*)d_in[0];
    float* out = (float*)d_out;
    const int nimg = in_sizes[0] / (512 * 512);   // 32*3 = 96
    const int total = nimg * 128 * 128;           // one thread per 4x4 tile
    const int block = 256;
    const int grid = (total + block - 1) / block; // 6144
    haar2_fused_kernel<<<grid, block, 0, stream>>>(x, out, nimg);
}